// Round 1
// baseline (1093.631 us; speedup 1.0000x reference)
//
#include <hip/hip_runtime.h>
#include <hip/hip_bf16.h>
#include <cstdint>

// MultiHeadAttention w/ sparsemax: B=2, S=2048, D=1024, H=16, DK=64
#define S_LEN  2048
#define DMODEL 1024
#define NHEAD  16
#define M_ROWS 4096                       // B*S

typedef __attribute__((ext_vector_type(8))) short bf16x8;   // MFMA A/B frag (8 bf16)
typedef __attribute__((ext_vector_type(4))) float f32x4;    // MFMA C/D frag

__device__ __forceinline__ unsigned short f2bf(float f) {
    __hip_bfloat16 h = __float2bfloat16(f);
    return __builtin_bit_cast(unsigned short, h);
}
__device__ __forceinline__ uint4 pack8(float4 a, float4 b) {
    uint4 u;
    u.x = ((unsigned)f2bf(a.y) << 16) | f2bf(a.x);
    u.y = ((unsigned)f2bf(a.w) << 16) | f2bf(a.z);
    u.z = ((unsigned)f2bf(b.y) << 16) | f2bf(b.x);
    u.w = ((unsigned)f2bf(b.w) << 16) | f2bf(b.z);
    return u;
}

// ------------------------------------- qkv: C = A@W^T + b (fp32 in, bf16 MFMA)
// A[4096,1024] fp32, W[1024,1024] fp32 (NT); inline fp32->bf16 in staging.
// Q,K: row-major bf16 [B*S, DMODEL].  V (which==2): TRANSPOSED [B,H,64,S]
// (V_t[((b*16+h)*64+d)*S + s]) so the fused PV can load B-frags contiguously.
__global__ __launch_bounds__(256)
void qkv_gemm(const float* __restrict__ xq, const float* __restrict__ xk,
              const float* __restrict__ xv,
              const float* __restrict__ Wq, const float* __restrict__ Wk,
              const float* __restrict__ Wv,
              const float* __restrict__ bq, const float* __restrict__ bk,
              const float* __restrict__ bv,
              unsigned short* __restrict__ Q_bf, unsigned short* __restrict__ K_bf,
              unsigned short* __restrict__ V_t) {
    const int which = blockIdx.z;
    const float* A    = (which == 0) ? xq : (which == 1) ? xk : xv;
    const float* W    = (which == 0) ? Wq : (which == 1) ? Wk : Wv;
    const float* bias = (which == 0) ? bq : (which == 1) ? bk : bv;
    unsigned short* dst = (which == 0) ? Q_bf : (which == 1) ? K_bf : V_t;

    const int row0 = blockIdx.x * 128;
    const int col0 = blockIdx.y * 128;

    __shared__ unsigned short SMEM[10240];    // As(5120) + Bs(5120); epilogue aliases
    unsigned short* As = SMEM;                // stride 40 bf16 (2-way free)
    unsigned short* Bs = SMEM + 5120;

    const int t = threadIdx.x;
    const int wid = t >> 6, lane = t & 63;
    const int wm = wid >> 1, wn = wid & 1;
    const int l = lane & 15, quad = lane >> 4;

    f32x4 acc[4][4];
#pragma unroll
    for (int i = 0; i < 4; ++i)
#pragma unroll
        for (int j = 0; j < 4; ++j) {
            float b_ = bias[col0 + wn * 64 + j * 16 + l];
            acc[i][j] = (f32x4){ b_, b_, b_, b_ };
        }

    for (int k0 = 0; k0 < DMODEL; k0 += 32) {
        uint4 ar[2], br[2];
#pragma unroll
        for (int i = 0; i < 2; ++i) {
            const int c = t + i * 256, r = c >> 2, q = (c & 3) * 8;
            const float* ap = A + (size_t)(row0 + r) * DMODEL + k0 + q;
            const float* wp = W + (size_t)(col0 + r) * DMODEL + k0 + q;
            float4 a0 = *(const float4*)ap, a1 = *(const float4*)(ap + 4);
            float4 w0 = *(const float4*)wp, w1 = *(const float4*)(wp + 4);
            ar[i] = pack8(a0, a1);
            br[i] = pack8(w0, w1);
        }
        __syncthreads();
#pragma unroll
        for (int i = 0; i < 2; ++i) {
            const int c = t + i * 256, r = c >> 2, q = (c & 3) * 8;
            *(uint4*)&As[r * 40 + q] = ar[i];
            *(uint4*)&Bs[r * 40 + q] = br[i];
        }
        __syncthreads();
        bf16x8 a[4], b[4];
#pragma unroll
        for (int i = 0; i < 4; ++i)
            a[i] = *(const bf16x8*)&As[(wm * 64 + i * 16 + l) * 40 + quad * 8];
#pragma unroll
        for (int j = 0; j < 4; ++j)
            b[j] = *(const bf16x8*)&Bs[(wn * 64 + j * 16 + l) * 40 + quad * 8];
#pragma unroll
        for (int i = 0; i < 4; ++i)
#pragma unroll
            for (int j = 0; j < 4; ++j)
                acc[i][j] = __builtin_amdgcn_mfma_f32_16x16x32_bf16(a[i], b[j], acc[i][j], 0, 0, 0);
    }

    // ---- epilogue: acc -> LDS (bf16, stride 72 = 16B-aligned rows) -> uint4 stores
    __syncthreads();
    unsigned short* Cs = SMEM;                // 128*72 = 9216 <= 10240
#pragma unroll 1
    for (int jh = 0; jh < 2; ++jh) {
        if (wn == jh) {
#pragma unroll
            for (int i = 0; i < 4; ++i)
#pragma unroll
                for (int j = 0; j < 4; ++j)
#pragma unroll
                    for (int r = 0; r < 4; ++r)
                        Cs[(wm * 64 + i * 16 + quad * 4 + r) * 72 + j * 16 + l] =
                            f2bf(acc[i][j][r]);
        }
        __syncthreads();
        if (which == 2) {
            // transposed store: V_t[((b*16+h)*64 + d)*S + s]
            const int h  = (col0 >> 6) + jh;
            const int b2 = row0 >> 11;            // 2048 % 128 == 0 -> uniform
            const int s0 = row0 & 2047;
#pragma unroll
            for (int it = 0; it < 4; ++it) {
                const int idx = t + it * 256;     // 0..1023
                const int d = idx & 63, sb = idx >> 6;
                union { unsigned short u[8]; uint4 v; } tmp;
#pragma unroll
                for (int j = 0; j < 8; ++j)
                    tmp.u[j] = Cs[(sb * 8 + j) * 72 + d];
                *(uint4*)(dst + ((size_t)((b2 * NHEAD + h) * 64 + d)) * S_LEN
                                + s0 + sb * 8) = tmp.v;
            }
        } else {
#pragma unroll
            for (int it = 0; it < 4; ++it) {
                const int idx = t + it * 256;           // 0..1023
                const int row = idx >> 3, c8 = (idx & 7) * 8;
                *(uint4*)(dst + (size_t)(row0 + row) * DMODEL + col0 + jh * 64 + c8) =
                    *(const uint4*)&Cs[row * 72 + c8];
            }
        }
        __syncthreads();
    }
}

// ------------------------- fused logits + sparsemax + PV -------------------------
// Block = 16 query rows x full 2048 cols of one (b,h). 8 waves, each owning a
// 256-col slice; z kept in registers (16 f32x4/lane). Newton tau via quad-shfl
// + cross-wave LDS reduce. One fp32 attn write; PV via MFMA with P staged bf16
// in XOR-swizzled LDS and V read from V_t (pre-transposed).
__global__ __launch_bounds__(512, 4)
void attn_fused(const unsigned short* __restrict__ Q_bf,
                const unsigned short* __restrict__ K_bf,
                const unsigned short* __restrict__ V_t,
                float* __restrict__ attn,
                unsigned short* __restrict__ AO_bf) {
    const int t = threadIdx.x;
    const int w = t >> 6, lane = t & 63;
    const int l = lane & 15, quad = lane >> 4;
    const int bh = blockIdx.y, b_ = bh >> 4, h = bh & 15;
    const int r0 = blockIdx.x * 16;

    __shared__ unsigned short Pl[16 * 2048];   // 64KB, col ^ ((row&7)<<3) swizzle
    __shared__ float redM[8][16];
    __shared__ float redS[2][8][16];
    __shared__ float redK[2][8][16];
    __shared__ float Obuf[4][256];             // 4KB cross-half PV reduce

    // ---- Q fragments (16 rows, K=64 -> two k-chunks)
    const unsigned short* Qp =
        Q_bf + ((size_t)(b_ * S_LEN + r0 + l)) * DMODEL + h * 64 + quad * 8;
    const bf16x8 a0 = *(const bf16x8*)Qp;
    const bf16x8 a1 = *(const bf16x8*)(Qp + 32);

    // ---- logits: this wave's cols [w*256, w*256+256)
    f32x4 acc[16];
    const unsigned short* Kb =
        K_bf + ((size_t)(b_ * S_LEN + w * 256 + l)) * DMODEL + h * 64 + quad * 8;
#pragma unroll
    for (int ct = 0; ct < 16; ++ct) {
        const unsigned short* Kp = Kb + (size_t)(ct * 16) * DMODEL;
        const bf16x8 b0 = *(const bf16x8*)Kp;
        const bf16x8 b1 = *(const bf16x8*)(Kp + 32);
        f32x4 c = {};
        c = __builtin_amdgcn_mfma_f32_16x16x32_bf16(a0, b0, c, 0, 0, 0);
        c = __builtin_amdgcn_mfma_f32_16x16x32_bf16(a1, b1, c, 0, 0, 0);
        acc[ct] = c;
    }
#pragma unroll
    for (int ct = 0; ct < 16; ++ct)
#pragma unroll
        for (int r = 0; r < 4; ++r) acc[ct][r] *= 0.125f;

    // ---- row max -> tau0 = max - 1  (rows live per-quad: row = quad*4 + r)
    float tau[4];
    {
        float mr[4] = { acc[0][0], acc[0][1], acc[0][2], acc[0][3] };
#pragma unroll
        for (int ct = 1; ct < 16; ++ct)
#pragma unroll
            for (int r = 0; r < 4; ++r) mr[r] = fmaxf(mr[r], acc[ct][r]);
#pragma unroll
        for (int r = 0; r < 4; ++r) {
            mr[r] = fmaxf(mr[r], __shfl_xor(mr[r], 1, 64));
            mr[r] = fmaxf(mr[r], __shfl_xor(mr[r], 2, 64));
            mr[r] = fmaxf(mr[r], __shfl_xor(mr[r], 4, 64));
            mr[r] = fmaxf(mr[r], __shfl_xor(mr[r], 8, 64));
        }
        if (l == 0) {
#pragma unroll
            for (int r = 0; r < 4; ++r) redM[w][quad * 4 + r] = mr[r];
        }
        __syncthreads();
#pragma unroll
        for (int r = 0; r < 4; ++r) {
            float M = redM[0][quad * 4 + r];
#pragma unroll
            for (int w2 = 1; w2 < 8; ++w2) M = fmaxf(M, redM[w2][quad * 4 + r]);
            tau[r] = M - 1.0f;
        }
    }

    // ---- Newton waterfilling: tau' = (sum_{z>tau} z - 1) / |{z>tau}|
#pragma unroll 1
    for (int it = 0; it < 8; ++it) {
        float ss[4] = {}, kk[4] = {};
#pragma unroll
        for (int ct = 0; ct < 16; ++ct)
#pragma unroll
            for (int r = 0; r < 4; ++r) {
                const float v = acc[ct][r];
                if (v > tau[r]) { ss[r] += v; kk[r] += 1.0f; }
            }
#pragma unroll
        for (int r = 0; r < 4; ++r) {
            ss[r] += __shfl_xor(ss[r], 1, 64); kk[r] += __shfl_xor(kk[r], 1, 64);
            ss[r] += __shfl_xor(ss[r], 2, 64); kk[r] += __shfl_xor(kk[r], 2, 64);
            ss[r] += __shfl_xor(ss[r], 4, 64); kk[r] += __shfl_xor(kk[r], 4, 64);
            ss[r] += __shfl_xor(ss[r], 8, 64); kk[r] += __shfl_xor(kk[r], 8, 64);
        }
        const int p = it & 1;
        if (l == 0) {
#pragma unroll
            for (int r = 0; r < 4; ++r) {
                redS[p][w][quad * 4 + r] = ss[r];
                redK[p][w][quad * 4 + r] = kk[r];
            }
        }
        __syncthreads();
#pragma unroll
        for (int r = 0; r < 4; ++r) {
            float S = 0.0f, C = 0.0f;
#pragma unroll
            for (int w2 = 0; w2 < 8; ++w2) {
                S += redS[p][w2][quad * 4 + r];
                C += redK[p][w2][quad * 4 + r];
            }
            tau[r] = (S - 1.0f) / C;
        }
    }

    // ---- p = max(z - tau, 0): into LDS (bf16, swizzled) first
#pragma unroll
    for (int ct = 0; ct < 16; ++ct) {
        const int col = w * 256 + ct * 16 + l;
#pragma unroll
        for (int r = 0; r < 4; ++r) {
            const int row = quad * 4 + r;
            const float pv = fmaxf(acc[ct][r] - tau[r], 0.0f);
            acc[ct][r] = pv;
            Pl[row * 2048 + (col ^ ((row & 7) << 3))] = f2bf(pv);
        }
    }
    __syncthreads();

    // ---- attn fp32 stores issue here (retire under PV compute)
    float* ap = attn + (size_t)bh * S_LEN * S_LEN;
#pragma unroll
    for (int ct = 0; ct < 16; ++ct) {
        const int col = w * 256 + ct * 16 + l;
#pragma unroll
        for (int r = 0; r < 4; ++r)
            ap[(size_t)(r0 + quad * 4 + r) * S_LEN + col] = acc[ct][r];
    }

    // ---- PV: O[16,64] = P[16,2048] @ V[2048,64]; wave = (ntile, khalf)
    const int nt = w & 3, kh = w >> 2;
    f32x4 oacc = {};
    const unsigned short* Vp =
        V_t + ((size_t)(bh * 64 + nt * 16 + l)) * S_LEN + kh * 1024 + quad * 8;
    const int sw = (l & 7) << 3;               // A-frag row = l
#pragma unroll 4
    for (int ks = 0; ks < 32; ++ks) {
        const int k0 = kh * 1024 + ks * 32 + quad * 8;
        const bf16x8 pa = *(const bf16x8*)&Pl[l * 2048 + (k0 ^ sw)];
        const bf16x8 vb = *(const bf16x8*)(Vp + ks * 32);
        oacc = __builtin_amdgcn_mfma_f32_16x16x32_bf16(pa, vb, oacc, 0, 0, 0);
    }
    if (kh == 1)
        *(float4*)&Obuf[nt][lane * 4] = (float4){ oacc[0], oacc[1], oacc[2], oacc[3] };
    __syncthreads();
    if (kh == 0) {
        const float4 o2 = *(const float4*)&Obuf[nt][lane * 4];
        oacc[0] += o2.x; oacc[1] += o2.y; oacc[2] += o2.z; oacc[3] += o2.w;
#pragma unroll
        for (int j = 0; j < 4; ++j)
            AO_bf[((size_t)(b_ * S_LEN + r0 + quad * 4 + j)) * DMODEL
                  + h * 64 + nt * 16 + l] = f2bf(oacc[j]);
    }
}

// ---------------------- out = AO @ Wfc^T + bfc (bf16 A, fp32 W inline-cast)
__global__ __launch_bounds__(256)
void fc_gemm(const unsigned short* __restrict__ AO_bf,
             const float* __restrict__ Wfc,
             const float* __restrict__ bfc, float* __restrict__ out) {
    const int row0 = blockIdx.x * 128;
    const int col0 = blockIdx.y * 128;

    __shared__ unsigned short As[128 * 40];
    __shared__ unsigned short Bs[128 * 40];

    const int t = threadIdx.x;
    const int wid = t >> 6, lane = t & 63;
    const int wm = wid >> 1, wn = wid & 1;
    const int l = lane & 15, quad = lane >> 4;

    f32x4 acc[4][4];
#pragma unroll
    for (int i = 0; i < 4; ++i)
#pragma unroll
        for (int j = 0; j < 4; ++j) {
            float b_ = bfc[col0 + wn * 64 + j * 16 + l];
            acc[i][j] = (f32x4){ b_, b_, b_, b_ };
        }

    for (int k0 = 0; k0 < DMODEL; k0 += 32) {
        uint4 ar[2], br[2];
#pragma unroll
        for (int i = 0; i < 2; ++i) {
            const int c = t + i * 256, r = c >> 2, q = (c & 3) * 8;
            ar[i] = *(const uint4*)(AO_bf + (size_t)(row0 + r) * DMODEL + k0 + q);
            const float* wp = Wfc + (size_t)(col0 + r) * DMODEL + k0 + q;
            float4 w0 = *(const float4*)wp, w1 = *(const float4*)(wp + 4);
            br[i] = pack8(w0, w1);
        }
        __syncthreads();
#pragma unroll
        for (int i = 0; i < 2; ++i) {
            const int c = t + i * 256, r = c >> 2, q = (c & 3) * 8;
            *(uint4*)&As[r * 40 + q] = ar[i];
            *(uint4*)&Bs[r * 40 + q] = br[i];
        }
        __syncthreads();
        bf16x8 a[4], b[4];
#pragma unroll
        for (int i = 0; i < 4; ++i)
            a[i] = *(const bf16x8*)&As[(wm * 64 + i * 16 + l) * 40 + quad * 8];
#pragma unroll
        for (int j = 0; j < 4; ++j)
            b[j] = *(const bf16x8*)&Bs[(wn * 64 + j * 16 + l) * 40 + quad * 8];
#pragma unroll
        for (int i = 0; i < 4; ++i)
#pragma unroll
            for (int j = 0; j < 4; ++j)
                acc[i][j] = __builtin_amdgcn_mfma_f32_16x16x32_bf16(a[i], b[j], acc[i][j], 0, 0, 0);
    }

#pragma unroll
    for (int i = 0; i < 4; ++i)
#pragma unroll
        for (int r = 0; r < 4; ++r) {
            const int m = row0 + wm * 64 + i * 16 + quad * 4 + r;
#pragma unroll
            for (int j = 0; j < 4; ++j) {
                const int n = col0 + wn * 64 + j * 16 + l;
                out[(size_t)m * DMODEL + n] = acc[i][j][r];
            }
        }
}

// ----------------------------------------------------------------------- launch
extern "C" void kernel_launch(void* const* d_in, const int* in_sizes, int n_in,
                              void* d_out, int out_size, void* d_ws, size_t ws_size,
                              hipStream_t stream) {
    const float* q   = (const float*)d_in[0];
    const float* k   = (const float*)d_in[1];
    const float* v   = (const float*)d_in[2];
    const float* Wq  = (const float*)d_in[3];
    const float* bq  = (const float*)d_in[4];
    const float* Wk  = (const float*)d_in[5];
    const float* bk  = (const float*)d_in[6];
    const float* Wv  = (const float*)d_in[7];
    const float* bv  = (const float*)d_in[8];
    const float* Wfc = (const float*)d_in[9];
    const float* bfc = (const float*)d_in[10];

    float* out  = (float*)d_out;                       // [B,S,D] fp32
    float* attn = out + (size_t)M_ROWS * DMODEL;       // [B,H,S,S] fp32

    // workspace: Q_bf [0,8M), K_bf [8,16M), V_t [16,24M), AO_bf [24,32M)
    char* ws = (char*)d_ws;
    unsigned short* Q_bf  = (unsigned short*)ws;
    unsigned short* K_bf  = (unsigned short*)(ws + (8u << 20));
    unsigned short* V_t   = (unsigned short*)(ws + (16u << 20));
    unsigned short* AO_bf = (unsigned short*)(ws + (24u << 20));

    qkv_gemm<<<dim3(32, 8, 3), 256, 0, stream>>>(q, k, v, Wq, Wk, Wv,
                                                  bq, bk, bv, Q_bf, K_bf, V_t);
    attn_fused<<<dim3(S_LEN / 16, 32), 512, 0, stream>>>(Q_bf, K_bf, V_t, attn, AO_bf);
    fc_gemm<<<dim3(32, 8), 256, 0, stream>>>(AO_bf, Wfc, bfc, out);
}

// Round 2
// 934.540 us; speedup vs baseline: 1.1702x; 1.1702x over previous
//
#include <hip/hip_runtime.h>
#include <hip/hip_bf16.h>
#include <cstdint>

// MultiHeadAttention w/ sparsemax: B=2, S=2048, D=1024, H=16, DK=64
#define S_LEN  2048
#define DMODEL 1024
#define NHEAD  16
#define M_ROWS 4096                       // B*S

typedef __attribute__((ext_vector_type(8))) short bf16x8;   // MFMA A/B frag (8 bf16)
typedef __attribute__((ext_vector_type(4))) float f32x4;    // MFMA C/D frag

__device__ __forceinline__ unsigned short f2bf(float f) {
    __hip_bfloat16 h = __float2bfloat16(f);
    return __builtin_bit_cast(unsigned short, h);
}
__device__ __forceinline__ float bf2f(unsigned short u) {
    return __builtin_bit_cast(float, (unsigned)u << 16);
}
__device__ __forceinline__ uint4 pack8(float4 a, float4 b) {
    uint4 u;
    u.x = ((unsigned)f2bf(a.y) << 16) | f2bf(a.x);
    u.y = ((unsigned)f2bf(a.w) << 16) | f2bf(a.z);
    u.z = ((unsigned)f2bf(b.y) << 16) | f2bf(b.x);
    u.w = ((unsigned)f2bf(b.w) << 16) | f2bf(b.z);
    return u;
}

// ---------------------------------------------------------------- wave reduce
__device__ __forceinline__ float wave_sum64(float v) {
    v += __shfl_xor(v, 32, 64); v += __shfl_xor(v, 16, 64);
    v += __shfl_xor(v, 8, 64);  v += __shfl_xor(v, 4, 64);
    v += __shfl_xor(v, 2, 64);  v += __shfl_xor(v, 1, 64);
    return v;
}
__device__ __forceinline__ float wave_max64(float v) {
    v = fmaxf(v, __shfl_xor(v, 32, 64)); v = fmaxf(v, __shfl_xor(v, 16, 64));
    v = fmaxf(v, __shfl_xor(v, 8, 64));  v = fmaxf(v, __shfl_xor(v, 4, 64));
    v = fmaxf(v, __shfl_xor(v, 2, 64));  v = fmaxf(v, __shfl_xor(v, 1, 64));
    return v;
}
__device__ __forceinline__ int lanes_below(unsigned long long m) {
    return __builtin_amdgcn_mbcnt_hi((unsigned)(m >> 32),
           __builtin_amdgcn_mbcnt_lo((unsigned)m, 0));
}

// ------------------------------------- qkv: C = A@W^T + b (fp32 in, bf16 MFMA)
// A[4096,1024] fp32, W[1024,1024] fp32 (NT); inline fp32->bf16 in staging.
// Output row-major bf16 [B,S,DMODEL] via LDS-transpose epilogue (16B stores).
__global__ __launch_bounds__(256)
void qkv_gemm(const float* __restrict__ xq, const float* __restrict__ xk,
              const float* __restrict__ xv,
              const float* __restrict__ Wq, const float* __restrict__ Wk,
              const float* __restrict__ Wv,
              const float* __restrict__ bq, const float* __restrict__ bk,
              const float* __restrict__ bv,
              unsigned short* __restrict__ Q_bf, unsigned short* __restrict__ K_bf,
              unsigned short* __restrict__ V_bf) {
    const int which = blockIdx.z;
    const float* A    = (which == 0) ? xq : (which == 1) ? xk : xv;
    const float* W    = (which == 0) ? Wq : (which == 1) ? Wk : Wv;
    const float* bias = (which == 0) ? bq : (which == 1) ? bk : bv;
    unsigned short* dst = (which == 0) ? Q_bf : (which == 1) ? K_bf : V_bf;

    const int row0 = blockIdx.x * 128;
    const int col0 = blockIdx.y * 128;

    __shared__ unsigned short SMEM[10240];    // As(5120) + Bs(5120); epilogue aliases
    unsigned short* As = SMEM;                // stride 40 bf16 (2-way free)
    unsigned short* Bs = SMEM + 5120;

    const int t = threadIdx.x;
    const int wid = t >> 6, lane = t & 63;
    const int wm = wid >> 1, wn = wid & 1;
    const int l = lane & 15, quad = lane >> 4;

    f32x4 acc[4][4];
#pragma unroll
    for (int i = 0; i < 4; ++i)
#pragma unroll
        for (int j = 0; j < 4; ++j) {
            float b_ = bias[col0 + wn * 64 + j * 16 + l];
            acc[i][j] = (f32x4){ b_, b_, b_, b_ };
        }

    for (int k0 = 0; k0 < DMODEL; k0 += 32) {
        uint4 ar[2], br[2];
#pragma unroll
        for (int i = 0; i < 2; ++i) {
            const int c = t + i * 256, r = c >> 2, q = (c & 3) * 8;
            const float* ap = A + (size_t)(row0 + r) * DMODEL + k0 + q;
            const float* wp = W + (size_t)(col0 + r) * DMODEL + k0 + q;
            float4 a0 = *(const float4*)ap, a1 = *(const float4*)(ap + 4);
            float4 w0 = *(const float4*)wp, w1 = *(const float4*)(wp + 4);
            ar[i] = pack8(a0, a1);
            br[i] = pack8(w0, w1);
        }
        __syncthreads();
#pragma unroll
        for (int i = 0; i < 2; ++i) {
            const int c = t + i * 256, r = c >> 2, q = (c & 3) * 8;
            *(uint4*)&As[r * 40 + q] = ar[i];
            *(uint4*)&Bs[r * 40 + q] = br[i];
        }
        __syncthreads();
        bf16x8 a[4], b[4];
#pragma unroll
        for (int i = 0; i < 4; ++i)
            a[i] = *(const bf16x8*)&As[(wm * 64 + i * 16 + l) * 40 + quad * 8];
#pragma unroll
        for (int j = 0; j < 4; ++j)
            b[j] = *(const bf16x8*)&Bs[(wn * 64 + j * 16 + l) * 40 + quad * 8];
#pragma unroll
        for (int i = 0; i < 4; ++i)
#pragma unroll
            for (int j = 0; j < 4; ++j)
                acc[i][j] = __builtin_amdgcn_mfma_f32_16x16x32_bf16(a[i], b[j], acc[i][j], 0, 0, 0);
    }

    // ---- epilogue: acc -> LDS (bf16, stride 72 = 16B-aligned rows) -> uint4 stores
    __syncthreads();
    unsigned short* Cs = SMEM;                // 128*72 = 9216 <= 10240
#pragma unroll 1
    for (int jh = 0; jh < 2; ++jh) {
        if (wn == jh) {
#pragma unroll
            for (int i = 0; i < 4; ++i)
#pragma unroll
                for (int j = 0; j < 4; ++j)
#pragma unroll
                    for (int r = 0; r < 4; ++r)
                        Cs[(wm * 64 + i * 16 + quad * 4 + r) * 72 + j * 16 + l] =
                            f2bf(acc[i][j][r]);
        }
        __syncthreads();
#pragma unroll
        for (int it = 0; it < 4; ++it) {
            const int idx = t + it * 256;           // 0..1023
            const int row = idx >> 3, c8 = (idx & 7) * 8;
            *(uint4*)(dst + (size_t)(row0 + row) * DMODEL + col0 + jh * 64 + c8) =
                *(const uint4*)&Cs[row * 72 + c8];
        }
        __syncthreads();
    }
}

// ------------------------- fused logits + sparsemax + sparse PV -------------------------
// Block = 16 query rows x full 2048 cols of one (b,h); 16 waves (1024 thr).
// Phase 1: QK^T via MFMA, wave w covers cols [w*128, w*128+128).
// Phase 2: LDS transpose (2 chunks of 8 rows, fp32) -> wave w owns row w
//          (z[32]/lane, z[j] = row[j*64+lane]).
// Phase 3: Newton waterfilling, fully wave-local (no barriers), early exit on
//          exact tau fixpoint (identical result to fixed 8 iters).
// Phase 4: p = max(z-tau,0); coalesced nontemporal fp32 attn row stores.
// Phase 5: ballot-compaction of nonzeros into per-wave LDS list (reuses the
//          transpose buffer) + sparse V-row gather (V row-major), AO store.
__global__ __launch_bounds__(1024, 4)
void attn_fused(const unsigned short* __restrict__ Q_bf,
                const unsigned short* __restrict__ K_bf,
                const unsigned short* __restrict__ V_bf,
                float* __restrict__ attn,
                unsigned short* __restrict__ AO_bf) {
    const int t = threadIdx.x;
    const int w = t >> 6, lane = t & 63;
    const int l = lane & 15, quad = lane >> 4;
    const int bh = blockIdx.y, b_ = bh >> 4, h = bh & 15;
    const int r0 = blockIdx.x * 16;

    __shared__ float LDSf[8 * 2048];   // 64 KB transpose buf; reused as gather lists

    // ---- Q fragments (block rows r0+l, K=64 -> two 32-d chunks)
    const unsigned short* Qp =
        Q_bf + ((size_t)(b_ * S_LEN + r0 + l)) * DMODEL + h * 64 + quad * 8;
    const bf16x8 a0 = *(const bf16x8*)Qp;
    const bf16x8 a1 = *(const bf16x8*)(Qp + 32);

    // ---- QK^T: this wave's cols [w*128, w*128+128)
    f32x4 acc[8];
    const unsigned short* Kb =
        K_bf + ((size_t)(b_ * S_LEN + w * 128 + l)) * DMODEL + h * 64 + quad * 8;
#pragma unroll
    for (int ct = 0; ct < 8; ++ct) {
        const unsigned short* Kp = Kb + (size_t)(ct * 16) * DMODEL;
        const bf16x8 b0 = *(const bf16x8*)Kp;
        const bf16x8 b1 = *(const bf16x8*)(Kp + 32);
        f32x4 c = {};
        c = __builtin_amdgcn_mfma_f32_16x16x32_bf16(a0, b0, c, 0, 0, 0);
        c = __builtin_amdgcn_mfma_f32_16x16x32_bf16(a1, b1, c, 0, 0, 0);
#pragma unroll
        for (int r = 0; r < 4; ++r) c[r] *= 0.125f;
        acc[ct] = c;
    }

    // ---- transpose to wave-owns-row: 2 chunks of 8 rows (rows = quad*4+r)
    float z[32];
#pragma unroll 1
    for (int c = 0; c < 2; ++c) {
        if ((quad >> 1) == c) {                    // this lane's rows in chunk c
            const int rb = (quad & 1) * 4;         // local row base in buffer
#pragma unroll
            for (int ct = 0; ct < 8; ++ct)
#pragma unroll
                for (int r = 0; r < 4; ++r)
                    LDSf[(rb + r) * 2048 + w * 128 + ct * 16 + l] = acc[ct][r];
        }
        __syncthreads();
        if ((w >> 3) == c) {                       // wave w reads row w
#pragma unroll
            for (int j = 0; j < 32; ++j)
                z[j] = LDSf[(w & 7) * 2048 + j * 64 + lane];
        }
        __syncthreads();
    }

    // ---- Newton waterfilling (wave-local; exact-fixpoint early exit)
    float m = z[0];
#pragma unroll
    for (int j = 1; j < 32; ++j) m = fmaxf(m, z[j]);
    m = wave_max64(m);

    float tau = m - 1.0f;
#pragma unroll 1
    for (int it = 0; it < 8; ++it) {
        float ss = 0.0f, kk = 0.0f;
#pragma unroll
        for (int j = 0; j < 32; ++j)
            if (z[j] > tau) { ss += z[j]; kk += 1.0f; }
        ss = wave_sum64(ss); kk = wave_sum64(kk);
        const float tn = (ss - 1.0f) / kk;         // uniform across wave
        if (tn == tau) break;                      // support stabilized -> done
        tau = tn;
    }

    // ---- p = max(z - tau, 0) in place; coalesced attn row store (256B/inst)
    float* ap = attn + (size_t)bh * S_LEN * S_LEN + (size_t)(r0 + w) * S_LEN;
#pragma unroll
    for (int j = 0; j < 32; ++j) {
        z[j] = fmaxf(z[j] - tau, 0.0f);
        __builtin_nontemporal_store(z[j], ap + j * 64 + lane);
    }

    // ---- sparse PV: compact nonzeros (col, p) per wave, gather V rows
    uint2* list = (uint2*)LDSf + w * 512;          // 4 KB/wave slice of LDSf
    const unsigned short* Vh = V_bf + ((size_t)b_ * S_LEN) * DMODEL + h * 64;
    float acco = 0.0f;
#pragma unroll
    for (int rr = 0; rr < 4; ++rr) {               // rounds of 8 j's (cap 512)
        int base = 0;
#pragma unroll
        for (int e = 0; e < 8; ++e) {
            const int j = rr * 8 + e;              // compile-time index into z
            const float pv = z[j];
            const unsigned long long mk = __ballot(pv > 0.0f);
            if (pv > 0.0f) {
                const int pos = base + lanes_below(mk);
                list[pos] = (uint2){ (unsigned)(j * 64 + lane),
                                     __builtin_bit_cast(unsigned, pv) };
            }
            base += __popcll(mk);
        }
        __threadfence_block();
        const int total = base;                    // wave-uniform
        int i = 0;
        for (; i + 2 <= total; i += 2) {
            uint2 k0 = list[i], k1 = list[i + 1];
            acco += __builtin_bit_cast(float, k0.y) *
                    bf2f(Vh[(size_t)k0.x * DMODEL + lane]);
            acco += __builtin_bit_cast(float, k1.y) *
                    bf2f(Vh[(size_t)k1.x * DMODEL + lane]);
        }
        if (i < total) {
            uint2 k0 = list[i];
            acco += __builtin_bit_cast(float, k0.y) *
                    bf2f(Vh[(size_t)k0.x * DMODEL + lane]);
        }
        __threadfence_block();
    }

    AO_bf[((size_t)(b_ * S_LEN + r0 + w)) * DMODEL + h * 64 + lane] = f2bf(acco);
}

// ---------------------- out = AO @ Wfc^T + bfc (bf16 A, fp32 W inline-cast)
__global__ __launch_bounds__(256)
void fc_gemm(const unsigned short* __restrict__ AO_bf,
             const float* __restrict__ Wfc,
             const float* __restrict__ bfc, float* __restrict__ out) {
    const int row0 = blockIdx.x * 128;
    const int col0 = blockIdx.y * 128;

    __shared__ unsigned short As[128 * 40];
    __shared__ unsigned short Bs[128 * 40];

    const int t = threadIdx.x;
    const int wid = t >> 6, lane = t & 63;
    const int wm = wid >> 1, wn = wid & 1;
    const int l = lane & 15, quad = lane >> 4;

    f32x4 acc[4][4];
#pragma unroll
    for (int i = 0; i < 4; ++i)
#pragma unroll
        for (int j = 0; j < 4; ++j) {
            float b_ = bfc[col0 + wn * 64 + j * 16 + l];
            acc[i][j] = (f32x4){ b_, b_, b_, b_ };
        }

    for (int k0 = 0; k0 < DMODEL; k0 += 32) {
        uint4 ar[2], br[2];
#pragma unroll
        for (int i = 0; i < 2; ++i) {
            const int c = t + i * 256, r = c >> 2, q = (c & 3) * 8;
            ar[i] = *(const uint4*)(AO_bf + (size_t)(row0 + r) * DMODEL + k0 + q);
            const float* wp = Wfc + (size_t)(col0 + r) * DMODEL + k0 + q;
            float4 w0 = *(const float4*)wp, w1 = *(const float4*)(wp + 4);
            br[i] = pack8(w0, w1);
        }
        __syncthreads();
#pragma unroll
        for (int i = 0; i < 2; ++i) {
            const int c = t + i * 256, r = c >> 2, q = (c & 3) * 8;
            *(uint4*)&As[r * 40 + q] = ar[i];
            *(uint4*)&Bs[r * 40 + q] = br[i];
        }
        __syncthreads();
        bf16x8 a[4], b[4];
#pragma unroll
        for (int i = 0; i < 4; ++i)
            a[i] = *(const bf16x8*)&As[(wm * 64 + i * 16 + l) * 40 + quad * 8];
#pragma unroll
        for (int j = 0; j < 4; ++j)
            b[j] = *(const bf16x8*)&Bs[(wn * 64 + j * 16 + l) * 40 + quad * 8];
#pragma unroll
        for (int i = 0; i < 4; ++i)
#pragma unroll
            for (int j = 0; j < 4; ++j)
                acc[i][j] = __builtin_amdgcn_mfma_f32_16x16x32_bf16(a[i], b[j], acc[i][j], 0, 0, 0);
    }

#pragma unroll
    for (int i = 0; i < 4; ++i)
#pragma unroll
        for (int r = 0; r < 4; ++r) {
            const int m = row0 + wm * 64 + i * 16 + quad * 4 + r;
#pragma unroll
            for (int j = 0; j < 4; ++j) {
                const int n = col0 + wn * 64 + j * 16 + l;
                out[(size_t)m * DMODEL + n] = acc[i][j][r];
            }
        }
}

// ----------------------------------------------------------------------- launch
extern "C" void kernel_launch(void* const* d_in, const int* in_sizes, int n_in,
                              void* d_out, int out_size, void* d_ws, size_t ws_size,
                              hipStream_t stream) {
    const float* q   = (const float*)d_in[0];
    const float* k   = (const float*)d_in[1];
    const float* v   = (const float*)d_in[2];
    const float* Wq  = (const float*)d_in[3];
    const float* bq  = (const float*)d_in[4];
    const float* Wk  = (const float*)d_in[5];
    const float* bk  = (const float*)d_in[6];
    const float* Wv  = (const float*)d_in[7];
    const float* bv  = (const float*)d_in[8];
    const float* Wfc = (const float*)d_in[9];
    const float* bfc = (const float*)d_in[10];

    float* out  = (float*)d_out;                       // [B,S,D] fp32
    float* attn = out + (size_t)M_ROWS * DMODEL;       // [B,H,S,S] fp32

    // workspace: Q_bf [0,8M), K_bf [8,16M), V_bf [16,24M), AO_bf [24,32M)
    char* ws = (char*)d_ws;
    unsigned short* Q_bf  = (unsigned short*)ws;
    unsigned short* K_bf  = (unsigned short*)(ws + (8u << 20));
    unsigned short* V_bf  = (unsigned short*)(ws + (16u << 20));
    unsigned short* AO_bf = (unsigned short*)(ws + (24u << 20));

    qkv_gemm<<<dim3(32, 8, 3), 256, 0, stream>>>(q, k, v, Wq, Wk, Wv,
                                                  bq, bk, bv, Q_bf, K_bf, V_bf);
    attn_fused<<<dim3(S_LEN / 16, 32), 1024, 0, stream>>>(Q_bf, K_bf, V_bf, attn, AO_bf);
    fc_gemm<<<dim3(32, 8), 256, 0, stream>>>(AO_bf, Wfc, bfc, out);
}

// Round 3
// 906.612 us; speedup vs baseline: 1.2063x; 1.0308x over previous
//
#include <hip/hip_runtime.h>
#include <hip/hip_bf16.h>
#include <cstdint>

// MultiHeadAttention w/ sparsemax: B=2, S=2048, D=1024, H=16, DK=64
#define S_LEN  2048
#define DMODEL 1024
#define NHEAD  16
#define M_ROWS 4096                       // B*S

typedef __attribute__((ext_vector_type(8))) short bf16x8;   // MFMA A/B frag (8 bf16)
typedef __attribute__((ext_vector_type(4))) float f32x4;    // MFMA C/D frag

__device__ __forceinline__ unsigned short f2bf(float f) {
    __hip_bfloat16 h = __float2bfloat16(f);
    return __builtin_bit_cast(unsigned short, h);
}
__device__ __forceinline__ float bf2f(unsigned short u) {
    return __builtin_bit_cast(float, (unsigned)u << 16);
}
__device__ __forceinline__ uint4 pack8(float4 a, float4 b) {
    uint4 u;
    u.x = ((unsigned)f2bf(a.y) << 16) | f2bf(a.x);
    u.y = ((unsigned)f2bf(a.w) << 16) | f2bf(a.z);
    u.z = ((unsigned)f2bf(b.y) << 16) | f2bf(b.x);
    u.w = ((unsigned)f2bf(b.w) << 16) | f2bf(b.z);
    return u;
}

// ---------------------------------------------------------------- wave reduce
__device__ __forceinline__ float wave_sum64(float v) {
    v += __shfl_xor(v, 32, 64); v += __shfl_xor(v, 16, 64);
    v += __shfl_xor(v, 8, 64);  v += __shfl_xor(v, 4, 64);
    v += __shfl_xor(v, 2, 64);  v += __shfl_xor(v, 1, 64);
    return v;
}
__device__ __forceinline__ float wave_max64(float v) {
    v = fmaxf(v, __shfl_xor(v, 32, 64)); v = fmaxf(v, __shfl_xor(v, 16, 64));
    v = fmaxf(v, __shfl_xor(v, 8, 64));  v = fmaxf(v, __shfl_xor(v, 4, 64));
    v = fmaxf(v, __shfl_xor(v, 2, 64));  v = fmaxf(v, __shfl_xor(v, 1, 64));
    return v;
}
__device__ __forceinline__ int lanes_below(unsigned long long m) {
    return __builtin_amdgcn_mbcnt_hi((unsigned)(m >> 32),
           __builtin_amdgcn_mbcnt_lo((unsigned)m, 0));
}

// ------------------------------------- qkv: C = A@W^T + b (fp32 in, bf16 MFMA)
// A[4096,1024] fp32, W[1024,1024] fp32 (NT); inline fp32->bf16 in staging.
// Output row-major bf16 [B,S,DMODEL] via LDS-transpose epilogue (16B stores).
__global__ __launch_bounds__(256)
void qkv_gemm(const float* __restrict__ xq, const float* __restrict__ xk,
              const float* __restrict__ xv,
              const float* __restrict__ Wq, const float* __restrict__ Wk,
              const float* __restrict__ Wv,
              const float* __restrict__ bq, const float* __restrict__ bk,
              const float* __restrict__ bv,
              unsigned short* __restrict__ Q_bf, unsigned short* __restrict__ K_bf,
              unsigned short* __restrict__ V_bf) {
    const int which = blockIdx.z;
    const float* A    = (which == 0) ? xq : (which == 1) ? xk : xv;
    const float* W    = (which == 0) ? Wq : (which == 1) ? Wk : Wv;
    const float* bias = (which == 0) ? bq : (which == 1) ? bk : bv;
    unsigned short* dst = (which == 0) ? Q_bf : (which == 1) ? K_bf : V_bf;

    const int row0 = blockIdx.x * 128;
    const int col0 = blockIdx.y * 128;

    __shared__ unsigned short SMEM[10240];    // As(5120) + Bs(5120); epilogue aliases
    unsigned short* As = SMEM;                // stride 40 bf16 (2-way free)
    unsigned short* Bs = SMEM + 5120;

    const int t = threadIdx.x;
    const int wid = t >> 6, lane = t & 63;
    const int wm = wid >> 1, wn = wid & 1;
    const int l = lane & 15, quad = lane >> 4;

    f32x4 acc[4][4];
#pragma unroll
    for (int i = 0; i < 4; ++i)
#pragma unroll
        for (int j = 0; j < 4; ++j) {
            float b_ = bias[col0 + wn * 64 + j * 16 + l];
            acc[i][j] = (f32x4){ b_, b_, b_, b_ };
        }

    for (int k0 = 0; k0 < DMODEL; k0 += 32) {
        uint4 ar[2], br[2];
#pragma unroll
        for (int i = 0; i < 2; ++i) {
            const int c = t + i * 256, r = c >> 2, q = (c & 3) * 8;
            const float* ap = A + (size_t)(row0 + r) * DMODEL + k0 + q;
            const float* wp = W + (size_t)(col0 + r) * DMODEL + k0 + q;
            float4 a0 = *(const float4*)ap, a1 = *(const float4*)(ap + 4);
            float4 w0 = *(const float4*)wp, w1 = *(const float4*)(wp + 4);
            ar[i] = pack8(a0, a1);
            br[i] = pack8(w0, w1);
        }
        __syncthreads();
#pragma unroll
        for (int i = 0; i < 2; ++i) {
            const int c = t + i * 256, r = c >> 2, q = (c & 3) * 8;
            *(uint4*)&As[r * 40 + q] = ar[i];
            *(uint4*)&Bs[r * 40 + q] = br[i];
        }
        __syncthreads();
        bf16x8 a[4], b[4];
#pragma unroll
        for (int i = 0; i < 4; ++i)
            a[i] = *(const bf16x8*)&As[(wm * 64 + i * 16 + l) * 40 + quad * 8];
#pragma unroll
        for (int j = 0; j < 4; ++j)
            b[j] = *(const bf16x8*)&Bs[(wn * 64 + j * 16 + l) * 40 + quad * 8];
#pragma unroll
        for (int i = 0; i < 4; ++i)
#pragma unroll
            for (int j = 0; j < 4; ++j)
                acc[i][j] = __builtin_amdgcn_mfma_f32_16x16x32_bf16(a[i], b[j], acc[i][j], 0, 0, 0);
    }

    // ---- epilogue: acc -> LDS (bf16, stride 72 = 16B-aligned rows) -> uint4 stores
    __syncthreads();
    unsigned short* Cs = SMEM;                // 128*72 = 9216 <= 10240
#pragma unroll 1
    for (int jh = 0; jh < 2; ++jh) {
        if (wn == jh) {
#pragma unroll
            for (int i = 0; i < 4; ++i)
#pragma unroll
                for (int j = 0; j < 4; ++j)
#pragma unroll
                    for (int r = 0; r < 4; ++r)
                        Cs[(wm * 64 + i * 16 + quad * 4 + r) * 72 + j * 16 + l] =
                            f2bf(acc[i][j][r]);
        }
        __syncthreads();
#pragma unroll
        for (int it = 0; it < 4; ++it) {
            const int idx = t + it * 256;           // 0..1023
            const int row = idx >> 3, c8 = (idx & 7) * 8;
            *(uint4*)(dst + (size_t)(row0 + row) * DMODEL + col0 + jh * 64 + c8) =
                *(const uint4*)&Cs[row * 72 + c8];
        }
        __syncthreads();
    }
}

// ------------------------- fused logits + sparsemax + sparse PV -------------------------
// Block = 8 query rows x 2048 cols of one (b,h); 8 waves (512 thr), wave owns row.
// QK^T in 4 column-quarters (acc[4] live) streamed through a 16 KB LDS transpose
// buffer -> z[32]/lane (z[q*8+j] = col q*512 + j*64 + lane). Newton tau is fully
// wave-local (shfl butterflies, early exit at exact fixpoint). Coalesced
// nontemporal fp32 attn stores. Sparse PV: single-pass ballot compaction of
// nonzeros into a 256-entry/wave list (aliases the LDS buffer), then gather
// 8 V-rows per memory instruction (8-lane subgroups x uint4) into acc8[8],
// stride-8 butterfly reduce, bf16x8 AO store.
// VGPR <= 64 (launch_bounds) + 16 KB LDS -> 4 blocks/CU = 32 waves (100%).
__global__ __launch_bounds__(512, 8)
void attn_fused(const unsigned short* __restrict__ Q_bf,
                const unsigned short* __restrict__ K_bf,
                const unsigned short* __restrict__ V_bf,
                float* __restrict__ attn,
                unsigned short* __restrict__ AO_bf) {
    const int t = threadIdx.x;
    const int w = t >> 6, lane = t & 63;
    const int l = lane & 15, quad = lane >> 4;
    const int bh = blockIdx.y, b_ = bh >> 4, h = bh & 15;
    const int r0 = blockIdx.x * 8;

    __shared__ float LDSf[8 * 512];    // 16 KB: transpose buf, then gather lists

    // ---- Q fragments: A rows l&7 -> C rows 0..7 valid (8..15 duplicates)
    const unsigned short* Qp =
        Q_bf + ((size_t)(b_ * S_LEN + r0 + (l & 7))) * DMODEL + h * 64 + quad * 8;
    const bf16x8 a0 = *(const bf16x8*)Qp;
    const bf16x8 a1 = *(const bf16x8*)(Qp + 32);

    float z[32];
    // ---- QK^T in 4 column-quarters; wave w covers cols q*512 + [w*64, w*64+64)
#pragma unroll
    for (int q = 0; q < 4; ++q) {
        const unsigned short* Kb =
            K_bf + ((size_t)(b_ * S_LEN + q * 512 + w * 64 + l)) * DMODEL
            + h * 64 + quad * 8;
        f32x4 acc[4];
#pragma unroll
        for (int ct = 0; ct < 4; ++ct) {
            const unsigned short* Kp = Kb + (size_t)(ct * 16) * DMODEL;
            const bf16x8 b0 = *(const bf16x8*)Kp;
            const bf16x8 b1 = *(const bf16x8*)(Kp + 32);
            f32x4 c = {};
            c = __builtin_amdgcn_mfma_f32_16x16x32_bf16(a0, b0, c, 0, 0, 0);
            c = __builtin_amdgcn_mfma_f32_16x16x32_bf16(a1, b1, c, 0, 0, 0);
#pragma unroll
            for (int r = 0; r < 4; ++r) c[r] *= 0.125f;
            acc[ct] = c;
        }
        // transpose: rows = quad*4+r (quads 0,1 hold real rows 0..7)
        if (quad < 2) {
#pragma unroll
            for (int ct = 0; ct < 4; ++ct)
#pragma unroll
                for (int r = 0; r < 4; ++r)
                    LDSf[(quad * 4 + r) * 512 + w * 64 + ct * 16 + l] = acc[ct][r];
        }
        __syncthreads();
#pragma unroll
        for (int j = 0; j < 8; ++j)
            z[q * 8 + j] = LDSf[w * 512 + j * 64 + lane];
        __syncthreads();
    }

    // ---- Newton waterfilling (wave-local; exact-fixpoint early exit)
    float m = z[0];
#pragma unroll
    for (int j = 1; j < 32; ++j) m = fmaxf(m, z[j]);
    m = wave_max64(m);

    float tau = m - 1.0f;
#pragma unroll 1
    for (int it = 0; it < 8; ++it) {
        float ss = 0.0f, kk = 0.0f;
#pragma unroll
        for (int j = 0; j < 32; ++j)
            if (z[j] > tau) { ss += z[j]; kk += 1.0f; }
        ss = wave_sum64(ss); kk = wave_sum64(kk);
        const float tn = (ss - 1.0f) / kk;         // uniform across wave
        if (tn == tau) break;                      // support stabilized -> done
        tau = tn;
    }

    // ---- p = max(z - tau, 0) in place; coalesced attn row store (256B/inst)
    float* ap = attn + (size_t)bh * S_LEN * S_LEN + (size_t)(r0 + w) * S_LEN;
#pragma unroll
    for (int jj = 0; jj < 32; ++jj) {
        z[jj] = fmaxf(z[jj] - tau, 0.0f);
        __builtin_nontemporal_store(z[jj], ap + (jj >> 3) * 512 + (jj & 7) * 64 + lane);
    }

    // ---- compact nonzeros (col, p) into per-wave list (single pass, cap 256)
    uint2* list = (uint2*)LDSf + w * 256;          // 2 KB/wave slice
    int base = 0;
#pragma unroll
    for (int jj = 0; jj < 32; ++jj) {
        const float pv = z[jj];
        const unsigned long long mk = __ballot(pv > 0.0f);
        if (pv > 0.0f) {
            const int pos = base + lanes_below(mk);
            if (pos < 256)
                list[pos] = (uint2){ (unsigned)((jj >> 3) * 512 + (jj & 7) * 64 + lane),
                                     __builtin_bit_cast(unsigned, pv) };
        }
        base += __popcll(mk);
    }
    const int cnt = base < 256 ? base : 256;       // wave-uniform
    __threadfence_block();

    // ---- gather: 8 V-rows per iteration (8-lane subgroups, uint4 each)
    const unsigned short* Vh = V_bf + ((size_t)b_ * S_LEN) * DMODEL + h * 64;
    const int sub = lane >> 3, dbase = (lane & 7) * 8;
    float acc8[8] = {};
    const int gmax = (cnt + 7) >> 3;
#pragma unroll 1
    for (int g = 0; g < gmax; ++g) {
        const int idx = g * 8 + sub;
        if (idx < cnt) {
            const uint2 e = list[idx];
            const float p = __builtin_bit_cast(float, e.y);
            const uint4 vv = *(const uint4*)(Vh + ((size_t)e.x) * DMODEL + dbase);
            acc8[0] += p * bf2f((unsigned short)(vv.x & 0xffff));
            acc8[1] += p * bf2f((unsigned short)(vv.x >> 16));
            acc8[2] += p * bf2f((unsigned short)(vv.y & 0xffff));
            acc8[3] += p * bf2f((unsigned short)(vv.y >> 16));
            acc8[4] += p * bf2f((unsigned short)(vv.z & 0xffff));
            acc8[5] += p * bf2f((unsigned short)(vv.z >> 16));
            acc8[6] += p * bf2f((unsigned short)(vv.w & 0xffff));
            acc8[7] += p * bf2f((unsigned short)(vv.w >> 16));
        }
    }
    // reduce across the 8 subgroups (stride-8 butterfly)
#pragma unroll
    for (int d = 0; d < 8; ++d) {
        acc8[d] += __shfl_xor(acc8[d], 8, 64);
        acc8[d] += __shfl_xor(acc8[d], 16, 64);
        acc8[d] += __shfl_xor(acc8[d], 32, 64);
    }
    if (lane < 8) {
        union { unsigned short u[8]; uint4 v; } o;
#pragma unroll
        for (int d = 0; d < 8; ++d) o.u[d] = f2bf(acc8[d]);
        *(uint4*)(AO_bf + ((size_t)(b_ * S_LEN + r0 + w)) * DMODEL
                  + h * 64 + lane * 8) = o.v;
    }
}

// ---------------------- out = AO @ Wfc^T + bfc (bf16 A, fp32 W inline-cast)
__global__ __launch_bounds__(256)
void fc_gemm(const unsigned short* __restrict__ AO_bf,
             const float* __restrict__ Wfc,
             const float* __restrict__ bfc, float* __restrict__ out) {
    const int row0 = blockIdx.x * 128;
    const int col0 = blockIdx.y * 128;

    __shared__ unsigned short As[128 * 40];
    __shared__ unsigned short Bs[128 * 40];

    const int t = threadIdx.x;
    const int wid = t >> 6, lane = t & 63;
    const int wm = wid >> 1, wn = wid & 1;
    const int l = lane & 15, quad = lane >> 4;

    f32x4 acc[4][4];
#pragma unroll
    for (int i = 0; i < 4; ++i)
#pragma unroll
        for (int j = 0; j < 4; ++j) {
            float b_ = bfc[col0 + wn * 64 + j * 16 + l];
            acc[i][j] = (f32x4){ b_, b_, b_, b_ };
        }

    for (int k0 = 0; k0 < DMODEL; k0 += 32) {
        uint4 ar[2], br[2];
#pragma unroll
        for (int i = 0; i < 2; ++i) {
            const int c = t + i * 256, r = c >> 2, q = (c & 3) * 8;
            ar[i] = *(const uint4*)(AO_bf + (size_t)(row0 + r) * DMODEL + k0 + q);
            const float* wp = Wfc + (size_t)(col0 + r) * DMODEL + k0 + q;
            float4 w0 = *(const float4*)wp, w1 = *(const float4*)(wp + 4);
            br[i] = pack8(w0, w1);
        }
        __syncthreads();
#pragma unroll
        for (int i = 0; i < 2; ++i) {
            const int c = t + i * 256, r = c >> 2, q = (c & 3) * 8;
            *(uint4*)&As[r * 40 + q] = ar[i];
            *(uint4*)&Bs[r * 40 + q] = br[i];
        }
        __syncthreads();
        bf16x8 a[4], b[4];
#pragma unroll
        for (int i = 0; i < 4; ++i)
            a[i] = *(const bf16x8*)&As[(wm * 64 + i * 16 + l) * 40 + quad * 8];
#pragma unroll
        for (int j = 0; j < 4; ++j)
            b[j] = *(const bf16x8*)&Bs[(wn * 64 + j * 16 + l) * 40 + quad * 8];
#pragma unroll
        for (int i = 0; i < 4; ++i)
#pragma unroll
            for (int j = 0; j < 4; ++j)
                acc[i][j] = __builtin_amdgcn_mfma_f32_16x16x32_bf16(a[i], b[j], acc[i][j], 0, 0, 0);
    }

#pragma unroll
    for (int i = 0; i < 4; ++i)
#pragma unroll
        for (int r = 0; r < 4; ++r) {
            const int m = row0 + wm * 64 + i * 16 + quad * 4 + r;
#pragma unroll
            for (int j = 0; j < 4; ++j) {
                const int n = col0 + wn * 64 + j * 16 + l;
                out[(size_t)m * DMODEL + n] = acc[i][j][r];
            }
        }
}

// ----------------------------------------------------------------------- launch
extern "C" void kernel_launch(void* const* d_in, const int* in_sizes, int n_in,
                              void* d_out, int out_size, void* d_ws, size_t ws_size,
                              hipStream_t stream) {
    const float* q   = (const float*)d_in[0];
    const float* k   = (const float*)d_in[1];
    const float* v   = (const float*)d_in[2];
    const float* Wq  = (const float*)d_in[3];
    const float* bq  = (const float*)d_in[4];
    const float* Wk  = (const float*)d_in[5];
    const float* bk  = (const float*)d_in[6];
    const float* Wv  = (const float*)d_in[7];
    const float* bv  = (const float*)d_in[8];
    const float* Wfc = (const float*)d_in[9];
    const float* bfc = (const float*)d_in[10];

    float* out  = (float*)d_out;                       // [B,S,D] fp32
    float* attn = out + (size_t)M_ROWS * DMODEL;       // [B,H,S,S] fp32

    // workspace: Q_bf [0,8M), K_bf [8,16M), V_bf [16,24M), AO_bf [24,32M)
    char* ws = (char*)d_ws;
    unsigned short* Q_bf  = (unsigned short*)ws;
    unsigned short* K_bf  = (unsigned short*)(ws + (8u << 20));
    unsigned short* V_bf  = (unsigned short*)(ws + (16u << 20));
    unsigned short* AO_bf = (unsigned short*)(ws + (24u << 20));

    qkv_gemm<<<dim3(32, 8, 3), 256, 0, stream>>>(q, k, v, Wq, Wk, Wv,
                                                  bq, bk, bv, Q_bf, K_bf, V_bf);
    attn_fused<<<dim3(S_LEN / 8, 32), 512, 0, stream>>>(Q_bf, K_bf, V_bf, attn, AO_bf);
    fc_gemm<<<dim3(32, 8), 256, 0, stream>>>(AO_bf, Wfc, bfc, out);
}

// Round 4
// 906.281 us; speedup vs baseline: 1.2067x; 1.0004x over previous
//
#include <hip/hip_runtime.h>
#include <hip/hip_bf16.h>
#include <cstdint>

// MultiHeadAttention w/ sparsemax: B=2, S=2048, D=1024, H=16, DK=64
#define S_LEN  2048
#define DMODEL 1024
#define NHEAD  16
#define M_ROWS 4096                       // B*S

typedef __attribute__((ext_vector_type(8))) short bf16x8;   // MFMA A/B frag (8 bf16)
typedef __attribute__((ext_vector_type(4))) float f32x4;    // MFMA C/D frag

__device__ __forceinline__ unsigned short f2bf(float f) {
    __hip_bfloat16 h = __float2bfloat16(f);
    return __builtin_bit_cast(unsigned short, h);
}
__device__ __forceinline__ float bf2f(unsigned short u) {
    return __builtin_bit_cast(float, (unsigned)u << 16);
}
__device__ __forceinline__ uint4 pack8(float4 a, float4 b) {
    uint4 u;
    u.x = ((unsigned)f2bf(a.y) << 16) | f2bf(a.x);
    u.y = ((unsigned)f2bf(a.w) << 16) | f2bf(a.z);
    u.z = ((unsigned)f2bf(b.y) << 16) | f2bf(b.x);
    u.w = ((unsigned)f2bf(b.w) << 16) | f2bf(b.z);
    return u;
}

// ---------------------------------------------------------------- wave reduce
__device__ __forceinline__ float wave_sum64(float v) {
    v += __shfl_xor(v, 32, 64); v += __shfl_xor(v, 16, 64);
    v += __shfl_xor(v, 8, 64);  v += __shfl_xor(v, 4, 64);
    v += __shfl_xor(v, 2, 64);  v += __shfl_xor(v, 1, 64);
    return v;
}
__device__ __forceinline__ float wave_max64(float v) {
    v = fmaxf(v, __shfl_xor(v, 32, 64)); v = fmaxf(v, __shfl_xor(v, 16, 64));
    v = fmaxf(v, __shfl_xor(v, 8, 64));  v = fmaxf(v, __shfl_xor(v, 4, 64));
    v = fmaxf(v, __shfl_xor(v, 2, 64));  v = fmaxf(v, __shfl_xor(v, 1, 64));
    return v;
}
__device__ __forceinline__ int lanes_below(unsigned long long m) {
    return __builtin_amdgcn_mbcnt_hi((unsigned)(m >> 32),
           __builtin_amdgcn_mbcnt_lo((unsigned)m, 0));
}

// ------------------------------------- qkv: C = A@W^T + b (fp32 in, bf16 MFMA)
// A[4096,1024] fp32, W[1024,1024] fp32 (NT); inline fp32->bf16 in staging.
// Output row-major bf16 [B,S,DMODEL] via LDS-transpose epilogue (16B stores).
// Q output (which==0) is pre-scaled by 0.125 (= 1/sqrt(DK)); power-of-2 scale
// is a pure exponent shift, so the bf16 rounding is bit-identical.
__global__ __launch_bounds__(256)
void qkv_gemm(const float* __restrict__ xq, const float* __restrict__ xk,
              const float* __restrict__ xv,
              const float* __restrict__ Wq, const float* __restrict__ Wk,
              const float* __restrict__ Wv,
              const float* __restrict__ bq, const float* __restrict__ bk,
              const float* __restrict__ bv,
              unsigned short* __restrict__ Q_bf, unsigned short* __restrict__ K_bf,
              unsigned short* __restrict__ V_bf) {
    const int which = blockIdx.z;
    const float* A    = (which == 0) ? xq : (which == 1) ? xk : xv;
    const float* W    = (which == 0) ? Wq : (which == 1) ? Wk : Wv;
    const float* bias = (which == 0) ? bq : (which == 1) ? bk : bv;
    unsigned short* dst = (which == 0) ? Q_bf : (which == 1) ? K_bf : V_bf;
    const float qscale = (which == 0) ? 0.125f : 1.0f;

    const int row0 = blockIdx.x * 128;
    const int col0 = blockIdx.y * 128;

    __shared__ unsigned short SMEM[10240];    // As(5120) + Bs(5120); epilogue aliases
    unsigned short* As = SMEM;                // stride 40 bf16 (2-way free)
    unsigned short* Bs = SMEM + 5120;

    const int t = threadIdx.x;
    const int wid = t >> 6, lane = t & 63;
    const int wm = wid >> 1, wn = wid & 1;
    const int l = lane & 15, quad = lane >> 4;

    f32x4 acc[4][4];
#pragma unroll
    for (int i = 0; i < 4; ++i)
#pragma unroll
        for (int j = 0; j < 4; ++j) {
            float b_ = bias[col0 + wn * 64 + j * 16 + l];
            acc[i][j] = (f32x4){ b_, b_, b_, b_ };
        }

    for (int k0 = 0; k0 < DMODEL; k0 += 32) {
        uint4 ar[2], br[2];
#pragma unroll
        for (int i = 0; i < 2; ++i) {
            const int c = t + i * 256, r = c >> 2, q = (c & 3) * 8;
            const float* ap = A + (size_t)(row0 + r) * DMODEL + k0 + q;
            const float* wp = W + (size_t)(col0 + r) * DMODEL + k0 + q;
            float4 a0 = *(const float4*)ap, a1 = *(const float4*)(ap + 4);
            float4 w0 = *(const float4*)wp, w1 = *(const float4*)(wp + 4);
            ar[i] = pack8(a0, a1);
            br[i] = pack8(w0, w1);
        }
        __syncthreads();
#pragma unroll
        for (int i = 0; i < 2; ++i) {
            const int c = t + i * 256, r = c >> 2, q = (c & 3) * 8;
            *(uint4*)&As[r * 40 + q] = ar[i];
            *(uint4*)&Bs[r * 40 + q] = br[i];
        }
        __syncthreads();
        bf16x8 a[4], b[4];
#pragma unroll
        for (int i = 0; i < 4; ++i)
            a[i] = *(const bf16x8*)&As[(wm * 64 + i * 16 + l) * 40 + quad * 8];
#pragma unroll
        for (int j = 0; j < 4; ++j)
            b[j] = *(const bf16x8*)&Bs[(wn * 64 + j * 16 + l) * 40 + quad * 8];
#pragma unroll
        for (int i = 0; i < 4; ++i)
#pragma unroll
            for (int j = 0; j < 4; ++j)
                acc[i][j] = __builtin_amdgcn_mfma_f32_16x16x32_bf16(a[i], b[j], acc[i][j], 0, 0, 0);
    }

    // ---- epilogue: acc -> LDS (bf16, stride 72 = 16B-aligned rows) -> uint4 stores
    __syncthreads();
    unsigned short* Cs = SMEM;                // 128*72 = 9216 <= 10240
#pragma unroll 1
    for (int jh = 0; jh < 2; ++jh) {
        if (wn == jh) {
#pragma unroll
            for (int i = 0; i < 4; ++i)
#pragma unroll
                for (int j = 0; j < 4; ++j)
#pragma unroll
                    for (int r = 0; r < 4; ++r)
                        Cs[(wm * 64 + i * 16 + quad * 4 + r) * 72 + j * 16 + l] =
                            f2bf(acc[i][j][r] * qscale);
        }
        __syncthreads();
#pragma unroll
        for (int it = 0; it < 4; ++it) {
            const int idx = t + it * 256;           // 0..1023
            const int row = idx >> 3, c8 = (idx & 7) * 8;
            *(uint4*)(dst + (size_t)(row0 + row) * DMODEL + col0 + jh * 64 + c8) =
                *(const uint4*)&Cs[row * 72 + c8];
        }
        __syncthreads();
    }
}

// ------------------------- fused logits + sparsemax + sparse PV -------------------------
// Block = 8 query rows x 2048 cols of one (b,h); 8 waves (512 thr), wave owns row.
// QK^T in 4 column-quarters streamed through a 16 KB LDS transpose region ->
// z[32]/lane. Key change vs v3: since Newton starts at tau0 = max-1 and tau is
// monotone increasing, elements z <= max-1 can never contribute -> compact
// candidates (col, z>max-1) FIRST (32 ballots), run Newton on the tiny
// candidate set (<= 4 regs/lane, usually 1), then reuse the same list for the
// sparse V gather with weight fmaxf(z - tau, 0). Fallback to full-register
// Newton if candidates > 256 (exactness; not expected for this data).
__global__ __launch_bounds__(512, 8)
void attn_fused(const unsigned short* __restrict__ Q_bf,
                const unsigned short* __restrict__ K_bf,
                const unsigned short* __restrict__ V_bf,
                float* __restrict__ attn,
                unsigned short* __restrict__ AO_bf) {
    const int t = threadIdx.x;
    const int w = t >> 6, lane = t & 63;
    const int l = lane & 15, quad = lane >> 4;
    const int bh = blockIdx.y, b_ = bh >> 4, h = bh & 15;
    const int r0 = blockIdx.x * 8;

    __shared__ uint2 List[8 * 512];    // 32 KB; first 16 KB aliased as transpose buf
    float* LDSf = (float*)List;

    // ---- Q fragments: A rows l&7 -> C rows 0..7 valid (8..15 duplicates)
    const unsigned short* Qp =
        Q_bf + ((size_t)(b_ * S_LEN + r0 + (l & 7))) * DMODEL + h * 64 + quad * 8;
    const bf16x8 a0 = *(const bf16x8*)Qp;
    const bf16x8 a1 = *(const bf16x8*)(Qp + 32);

    float z[32];
    // ---- QK^T in 4 column-quarters; wave w covers cols q*512 + [w*64, w*64+64)
#pragma unroll
    for (int q = 0; q < 4; ++q) {
        const unsigned short* Kb =
            K_bf + ((size_t)(b_ * S_LEN + q * 512 + w * 64 + l)) * DMODEL
            + h * 64 + quad * 8;
        f32x4 acc[4];
#pragma unroll
        for (int ct = 0; ct < 4; ++ct) {
            const unsigned short* Kp = Kb + (size_t)(ct * 16) * DMODEL;
            const bf16x8 b0 = *(const bf16x8*)Kp;
            const bf16x8 b1 = *(const bf16x8*)(Kp + 32);
            f32x4 c = {};
            c = __builtin_amdgcn_mfma_f32_16x16x32_bf16(a0, b0, c, 0, 0, 0);
            c = __builtin_amdgcn_mfma_f32_16x16x32_bf16(a1, b1, c, 0, 0, 0);
            acc[ct] = c;                           // Q pre-scaled by 1/8 in qkv
        }
        // transpose: rows = quad*4+r (quads 0,1 hold real rows 0..7)
        if (quad < 2) {
#pragma unroll
            for (int ct = 0; ct < 4; ++ct)
#pragma unroll
                for (int r = 0; r < 4; ++r)
                    LDSf[(quad * 4 + r) * 512 + w * 64 + ct * 16 + l] = acc[ct][r];
        }
        __syncthreads();
#pragma unroll
        for (int j = 0; j < 8; ++j)
            z[q * 8 + j] = LDSf[w * 512 + j * 64 + lane];
        __syncthreads();
    }

    // ---- row max; candidate threshold thr = m - 1 (tau* >= m-1 always)
    float m = z[0];
#pragma unroll
    for (int j = 1; j < 32; ++j) m = fmaxf(m, z[j]);
    m = wave_max64(m);
    const float thr = m - 1.0f;

    // ---- candidate compaction: (col, z) with z > thr, per-wave list
    uint2* list = List + w * 512;
    int cnt = 0;
#pragma unroll
    for (int jj = 0; jj < 32; ++jj) {
        const float zv = z[jj];
        const unsigned long long mk = __ballot(zv > thr);
        if (zv > thr) {
            const int pos = cnt + lanes_below(mk);
            if (pos < 512)
                list[pos] = (uint2){ (unsigned)((jj >> 3) * 512 + (jj & 7) * 64 + lane),
                                     __builtin_bit_cast(unsigned, zv) };
        }
        cnt += __popcll(mk);
    }
    __threadfence_block();

    // ---- Newton waterfilling on candidates (common) or full scan (fallback)
    float tau = thr;
    if (cnt <= 256) {
        const float NEG = -__builtin_inff();
        const float zc0 = (lane < cnt)
            ? __builtin_bit_cast(float, list[lane].y) : NEG;
        const float zc1 = (64 + lane < cnt)
            ? __builtin_bit_cast(float, list[64 + lane].y) : NEG;
        const float zc2 = (128 + lane < cnt)
            ? __builtin_bit_cast(float, list[128 + lane].y) : NEG;
        const float zc3 = (192 + lane < cnt)
            ? __builtin_bit_cast(float, list[192 + lane].y) : NEG;
#pragma unroll 1
        for (int it = 0; it < 12; ++it) {
            float ss = 0.0f, kk = 0.0f;
            if (zc0 > tau) { ss += zc0; kk += 1.0f; }
            if (zc1 > tau) { ss += zc1; kk += 1.0f; }
            if (zc2 > tau) { ss += zc2; kk += 1.0f; }
            if (zc3 > tau) { ss += zc3; kk += 1.0f; }
            ss = wave_sum64(ss); kk = wave_sum64(kk);
            const float tn = (ss - 1.0f) / kk;     // uniform across wave
            if (tn == tau) break;                  // support stabilized -> exact
            tau = tn;
        }
    } else {
#pragma unroll 1
        for (int it = 0; it < 8; ++it) {
            float ss = 0.0f, kk = 0.0f;
#pragma unroll
            for (int j = 0; j < 32; ++j)
                if (z[j] > tau) { ss += z[j]; kk += 1.0f; }
            ss = wave_sum64(ss); kk = wave_sum64(kk);
            const float tn = (ss - 1.0f) / kk;
            if (tn == tau) break;
            tau = tn;
        }
        // recompact: support only (z > tau), same (col, z) entry format
        cnt = 0;
#pragma unroll
        for (int jj = 0; jj < 32; ++jj) {
            const float zv = z[jj];
            const unsigned long long mk = __ballot(zv > tau);
            if (zv > tau) {
                const int pos = cnt + lanes_below(mk);
                if (pos < 512)
                    list[pos] = (uint2){ (unsigned)((jj >> 3) * 512 + (jj & 7) * 64 + lane),
                                         __builtin_bit_cast(unsigned, zv) };
            }
            cnt += __popcll(mk);
        }
        __threadfence_block();
    }
    if (cnt > 504) cnt = 504;                      // keep pad + reads in bounds

    // ---- p = max(z - tau, 0); coalesced nontemporal fp32 attn row store
    float* ap = attn + (size_t)bh * S_LEN * S_LEN + (size_t)(r0 + w) * S_LEN;
#pragma unroll
    for (int jj = 0; jj < 32; ++jj) {
        const float pv = fmaxf(z[jj] - tau, 0.0f);
        __builtin_nontemporal_store(pv, ap + (jj >> 3) * 512 + (jj & 7) * 64 + lane);
    }

    // ---- pad list to a multiple of 8 with -inf entries (guard-free gather)
    if (lane < 8)
        list[cnt + lane] = (uint2){ 0u, 0xff800000u };   // z = -inf -> p = 0
    __threadfence_block();

    // ---- gather: 8 V-rows per iteration (8-lane subgroups, uint4 each)
    const unsigned short* Vh = V_bf + ((size_t)b_ * S_LEN) * DMODEL + h * 64;
    const int sub = lane >> 3, dbase = (lane & 7) * 8;
    float acc8[8] = {};
    const int gmax = (cnt + 7) >> 3;
#pragma unroll 2
    for (int g = 0; g < gmax; ++g) {
        const uint2 e = list[g * 8 + sub];
        const float p = fmaxf(__builtin_bit_cast(float, e.y) - tau, 0.0f);
        const uint4 vv = *(const uint4*)(Vh + ((size_t)e.x) * DMODEL + dbase);
        acc8[0] += p * bf2f((unsigned short)(vv.x & 0xffff));
        acc8[1] += p * bf2f((unsigned short)(vv.x >> 16));
        acc8[2] += p * bf2f((unsigned short)(vv.y & 0xffff));
        acc8[3] += p * bf2f((unsigned short)(vv.y >> 16));
        acc8[4] += p * bf2f((unsigned short)(vv.z & 0xffff));
        acc8[5] += p * bf2f((unsigned short)(vv.z >> 16));
        acc8[6] += p * bf2f((unsigned short)(vv.w & 0xffff));
        acc8[7] += p * bf2f((unsigned short)(vv.w >> 16));
    }
    // reduce across the 8 subgroups (stride-8 butterfly)
#pragma unroll
    for (int d = 0; d < 8; ++d) {
        acc8[d] += __shfl_xor(acc8[d], 8, 64);
        acc8[d] += __shfl_xor(acc8[d], 16, 64);
        acc8[d] += __shfl_xor(acc8[d], 32, 64);
    }
    if (lane < 8) {
        union { unsigned short u[8]; uint4 v; } o;
#pragma unroll
        for (int d = 0; d < 8; ++d) o.u[d] = f2bf(acc8[d]);
        *(uint4*)(AO_bf + ((size_t)(b_ * S_LEN + r0 + w)) * DMODEL
                  + h * 64 + lane * 8) = o.v;
    }
}

// ---------------------- out = AO @ Wfc^T + bfc (bf16 A, fp32 W inline-cast)
__global__ __launch_bounds__(256)
void fc_gemm(const unsigned short* __restrict__ AO_bf,
             const float* __restrict__ Wfc,
             const float* __restrict__ bfc, float* __restrict__ out) {
    const int row0 = blockIdx.x * 128;
    const int col0 = blockIdx.y * 128;

    __shared__ unsigned short As[128 * 40];
    __shared__ unsigned short Bs[128 * 40];

    const int t = threadIdx.x;
    const int wid = t >> 6, lane = t & 63;
    const int wm = wid >> 1, wn = wid & 1;
    const int l = lane & 15, quad = lane >> 4;

    f32x4 acc[4][4];
#pragma unroll
    for (int i = 0; i < 4; ++i)
#pragma unroll
        for (int j = 0; j < 4; ++j) {
            float b_ = bfc[col0 + wn * 64 + j * 16 + l];
            acc[i][j] = (f32x4){ b_, b_, b_, b_ };
        }

    for (int k0 = 0; k0 < DMODEL; k0 += 32) {
        uint4 ar[2], br[2];
#pragma unroll
        for (int i = 0; i < 2; ++i) {
            const int c = t + i * 256, r = c >> 2, q = (c & 3) * 8;
            ar[i] = *(const uint4*)(AO_bf + (size_t)(row0 + r) * DMODEL + k0 + q);
            const float* wp = Wfc + (size_t)(col0 + r) * DMODEL + k0 + q;
            float4 w0 = *(const float4*)wp, w1 = *(const float4*)(wp + 4);
            br[i] = pack8(w0, w1);
        }
        __syncthreads();
#pragma unroll
        for (int i = 0; i < 2; ++i) {
            const int c = t + i * 256, r = c >> 2, q = (c & 3) * 8;
            *(uint4*)&As[r * 40 + q] = ar[i];
            *(uint4*)&Bs[r * 40 + q] = br[i];
        }
        __syncthreads();
        bf16x8 a[4], b[4];
#pragma unroll
        for (int i = 0; i < 4; ++i)
            a[i] = *(const bf16x8*)&As[(wm * 64 + i * 16 + l) * 40 + quad * 8];
#pragma unroll
        for (int j = 0; j < 4; ++j)
            b[j] = *(const bf16x8*)&Bs[(wn * 64 + j * 16 + l) * 40 + quad * 8];
#pragma unroll
        for (int i = 0; i < 4; ++i)
#pragma unroll
            for (int j = 0; j < 4; ++j)
                acc[i][j] = __builtin_amdgcn_mfma_f32_16x16x32_bf16(a[i], b[j], acc[i][j], 0, 0, 0);
    }

#pragma unroll
    for (int i = 0; i < 4; ++i)
#pragma unroll
        for (int r = 0; r < 4; ++r) {
            const int m = row0 + wm * 64 + i * 16 + quad * 4 + r;
#pragma unroll
            for (int j = 0; j < 4; ++j) {
                const int n = col0 + wn * 64 + j * 16 + l;
                out[(size_t)m * DMODEL + n] = acc[i][j][r];
            }
        }
}

// ----------------------------------------------------------------------- launch
extern "C" void kernel_launch(void* const* d_in, const int* in_sizes, int n_in,
                              void* d_out, int out_size, void* d_ws, size_t ws_size,
                              hipStream_t stream) {
    const float* q   = (const float*)d_in[0];
    const float* k   = (const float*)d_in[1];
    const float* v   = (const float*)d_in[2];
    const float* Wq  = (const float*)d_in[3];
    const float* bq  = (const float*)d_in[4];
    const float* Wk  = (const float*)d_in[5];
    const float* bk  = (const float*)d_in[6];
    const float* Wv  = (const float*)d_in[7];
    const float* bv  = (const float*)d_in[8];
    const float* Wfc = (const float*)d_in[9];
    const float* bfc = (const float*)d_in[10];

    float* out  = (float*)d_out;                       // [B,S,D] fp32
    float* attn = out + (size_t)M_ROWS * DMODEL;       // [B,H,S,S] fp32

    // workspace: Q_bf [0,8M), K_bf [8,16M), V_bf [16,24M), AO_bf [24,32M)
    char* ws = (char*)d_ws;
    unsigned short* Q_bf  = (unsigned short*)ws;
    unsigned short* K_bf  = (unsigned short*)(ws + (8u << 20));
    unsigned short* V_bf  = (unsigned short*)(ws + (16u << 20));
    unsigned short* AO_bf = (unsigned short*)(ws + (24u << 20));

    qkv_gemm<<<dim3(32, 8, 3), 256, 0, stream>>>(q, k, v, Wq, Wk, Wv,
                                                  bq, bk, bv, Q_bf, K_bf, V_bf);
    attn_fused<<<dim3(S_LEN / 8, 32), 512, 0, stream>>>(Q_bf, K_bf, V_bf, attn, AO_bf);
    fc_gemm<<<dim3(32, 8), 256, 0, stream>>>(AO_bf, Wfc, bfc, out);
}